// Round 3
// baseline (71.387 us; speedup 1.0000x reference)
//
#include <hip/hip_runtime.h>

// Closed-form quanv (derivation verified on HW in round 1, absmax 0.0):
//   f0 = cos(q0)*cos(a0)
//   f1 = f0*cos(a1+q1)
//   f2 = f1*(cos(q4)*cos(a2) - sin(q4)*cos(q2)*sin(a2)*sin(a3))
//   f3 = cos(q3)*cos(a2)*cos(a3)
// where a[w] = patch . embW[w,:] + embB[w].
//
// Round-2 structure: IMGS=4 images per block (grid B/4) to amortize
// per-block overheads and linW L2 traffic (each linW float4 is read once
// and dotted against 4 images' feats).
#define IMGS 4

__global__ __launch_bounds__(256) void quanv_fused(
    const float* __restrict__ x,      // (B, 784)
    const float* __restrict__ embW,   // (4, 4) row-major
    const float* __restrict__ embB,   // (4,)
    const float* __restrict__ qp,     // (5,)
    const float* __restrict__ linW,   // (10, 784) row-major
    const float* __restrict__ linB,   // (10,)
    float* __restrict__ out,          // (B, 10)
    int B)
{
    const int b0  = blockIdx.x * IMGS;
    const int tid = threadIdx.x;
    const int nimg = (B - b0 < IMGS) ? (B - b0) : IMGS;

    __shared__ float  ximg[IMGS * 784];       // raw pixels, 12.25 KB
    __shared__ float4 sfeats[IMGS * 196];     // feats per (img, patch), 12.25 KB
    __shared__ float  slog[IMGS * 10];

    // --- Stage x: fully coalesced float4 loads (196 float4 per image). ---
    {
        const float4* xg = reinterpret_cast<const float4*>(x + (size_t)b0 * 784);
        float4* xs = reinterpret_cast<float4*>(ximg);
        for (int i = tid; i < nimg * 196; i += 256) xs[i] = xg[i];
    }

    // Uniform circuit constants (lane-uniform, scalarized).
    const float Q0 = __cosf(qp[0]);
    float s4, c4; __sincosf(qp[4], &s4, &c4);
    const float S4C2 = s4 * __cosf(qp[2]);
    const float Q3 = __cosf(qp[3]);
    const float Q1 = qp[1];

    __syncthreads();

    // --- Phase 1: feats for nimg*196 patch-tasks (<= 784, up to 4/thread). ---
    for (int t = tid; t < nimg * 196; t += 256) {
        const int img = t / 196;
        const int p   = t - img * 196;
        const unsigned pi = (unsigned)p / 14u, pj = (unsigned)p % 14u;
        const float* im = ximg + img * 784;
        const float p0 = im[(2 * pi) * 28 + 2 * pj];
        const float p1 = im[(2 * pi) * 28 + 2 * pj + 1];
        const float p2 = im[(2 * pi + 1) * 28 + 2 * pj];
        const float p3 = im[(2 * pi + 1) * 28 + 2 * pj + 1];

        const float a0 = embB[0] + embW[0]  * p0 + embW[1]  * p1 + embW[2]  * p2 + embW[3]  * p3;
        const float a1 = embB[1] + embW[4]  * p0 + embW[5]  * p1 + embW[6]  * p2 + embW[7]  * p3;
        const float a2 = embB[2] + embW[8]  * p0 + embW[9]  * p1 + embW[10] * p2 + embW[11] * p3;
        const float a3 = embB[3] + embW[12] * p0 + embW[13] * p1 + embW[14] * p2 + embW[15] * p3;

        const float c0 = __cosf(a0);
        const float c1 = __cosf(a1 + Q1);
        float s2, c2; __sincosf(a2, &s2, &c2);
        float s3, c3; __sincosf(a3, &s3, &c3);

        const float f0 = Q0 * c0;
        const float f1 = f0 * c1;
        const float f2 = f1 * (c4 * c2 - S4C2 * s2 * s3);
        const float f3 = Q3 * c2 * c3;
        sfeats[t] = make_float4(f0, f1, f2, f3);
    }
    // Zero-fill missing-image feats so phase 2 can accumulate unconditionally.
    for (int t = nimg * 196 + tid; t < IMGS * 196; t += 256)
        sfeats[t] = make_float4(0.f, 0.f, 0.f, 0.f);
    __syncthreads();

    // --- Phase 2: thread (c, j) dots channel c, patches j::16, for ALL 4
    //     images at once (each linW float4 read exactly once per block). ---
    if (tid < 160) {
        const int c = tid >> 4;
        const int j = tid & 15;
        float acc[IMGS] = {0.f, 0.f, 0.f, 0.f};
        for (int p = j; p < 196; p += 16) {
            const float4 wv = *reinterpret_cast<const float4*>(linW + c * 784 + 4 * p);
            #pragma unroll
            for (int i = 0; i < IMGS; ++i) {
                const float4 f = sfeats[i * 196 + p];
                acc[i] += f.x * wv.x + f.y * wv.y + f.z * wv.z + f.w * wv.w;
            }
        }
        #pragma unroll
        for (int i = 0; i < IMGS; ++i) {
            acc[i] += __shfl_xor(acc[i], 8);
            acc[i] += __shfl_xor(acc[i], 4);
            acc[i] += __shfl_xor(acc[i], 2);
            acc[i] += __shfl_xor(acc[i], 1);
        }
        if (j == 0) {
            #pragma unroll
            for (int i = 0; i < IMGS; ++i) slog[i * 10 + c] = acc[i];
        }
    }
    __syncthreads();

    // --- Phase 3: log_softmax, 16 lanes per image, 4 images in wave 0. ---
    if (tid < 16 * IMGS) {
        const int img = tid >> 4;
        const int l   = tid & 15;
        const float logit = (l < 10) ? (slog[img * 10 + l] + linB[l]) : -1e30f;
        float m = logit;
        m = fmaxf(m, __shfl_xor(m, 1, 16));
        m = fmaxf(m, __shfl_xor(m, 2, 16));
        m = fmaxf(m, __shfl_xor(m, 4, 16));
        m = fmaxf(m, __shfl_xor(m, 8, 16));
        float e = (l < 10) ? expf(logit - m) : 0.0f;
        e += __shfl_xor(e, 1, 16);
        e += __shfl_xor(e, 2, 16);
        e += __shfl_xor(e, 4, 16);
        e += __shfl_xor(e, 8, 16);
        const float lse = m + logf(e);
        if (l < 10 && img < nimg) out[(size_t)(b0 + img) * 10 + l] = logit - lse;
    }
}

extern "C" void kernel_launch(void* const* d_in, const int* in_sizes, int n_in,
                              void* d_out, int out_size, void* d_ws, size_t ws_size,
                              hipStream_t stream) {
    const float* x    = (const float*)d_in[0];
    const float* embW = (const float*)d_in[1];
    const float* embB = (const float*)d_in[2];
    const float* qp   = (const float*)d_in[3];
    const float* linW = (const float*)d_in[4];
    const float* linB = (const float*)d_in[5];
    float* out = (float*)d_out;

    const int B = in_sizes[0] / 784;
    const int grid = (B + IMGS - 1) / IMGS;
    quanv_fused<<<grid, 256, 0, stream>>>(x, embW, embB, qp, linW, linB, out, B);
}